// Round 1
// baseline (268.431 us; speedup 1.0000x reference)
//
#include <hip/hip_runtime.h>
#include <hip/hip_bf16.h>
#include <math.h>

#define HW 9216      // 96*96
#define C2 64
#define NCHUNK 16    // j-split factor
#define EPSN 1e-8f

// ---------------- kernel 1: copy former+latter passthrough ----------------
// out[b, 0:128, :] = x[b, :, :]  (channels contiguous -> block copy per b)
__global__ void copy_kernel(const float4* __restrict__ x4, float4* __restrict__ out4) {
    int t = blockIdx.x * blockDim.x + threadIdx.x;   // 0 .. 2*128*9216/4-1
    const int perb = 128 * HW / 4;                   // 294912
    if (t >= 2 * perb) return;
    int b = t / perb, r = t - b * perb;
    out4[(size_t)b * (192 * HW / 4) + r] = x4[(size_t)b * perb + r];
}

// ---------------- kernel 2: compaction (single block, 1024 threads) -------
// ilist = positions with mask>=1 (flagged i), jlist = positions with mask<1
__global__ void compact_kernel(const int* __restrict__ mask, int* __restrict__ ilist,
                               int* __restrict__ jlist, int* __restrict__ counts) {
    __shared__ int sc[1024];
    int t = threadIdx.x;
    int base = t * 9;
    int f[9]; int cnt = 0;
#pragma unroll
    for (int k = 0; k < 9; k++) { f[k] = (mask[base + k] >= 1) ? 1 : 0; cnt += f[k]; }
    sc[t] = cnt;
    __syncthreads();
#pragma unroll
    for (int off = 1; off < 1024; off <<= 1) {
        int add = (t >= off) ? sc[t - off] : 0;
        __syncthreads();
        sc[t] += add;
        __syncthreads();
    }
    int incl = sc[t];
    int excl = incl - cnt;
    int posF = excl, posU = base - excl;
#pragma unroll
    for (int k = 0; k < 9; k++) {
        int p = base + k;
        if (f[k]) ilist[posF++] = p; else jlist[posU++] = p;
    }
    if (t == 1023) { counts[0] = incl; counts[1] = HW - incl; }
}

// ---------------- kernel 3: build normalized, compacted B matrix ----------
// bmat[b][jj][c] = lat[b][jlist[jj]][c] / max(||lat_j||, eps)   (contiguous 64f per jj)
__global__ void buildb_kernel(const float* __restrict__ x, const int* __restrict__ jlist,
                              const int* __restrict__ counts, float* __restrict__ bmat) {
    int t = blockIdx.x * blockDim.x + threadIdx.x;   // 0 .. 2*HW-1
    if (t >= 2 * HW) return;
    int b = t / HW, jj = t - b * HW;
    int nj = counts[1];
    if (jj >= nj) return;
    int j = jlist[jj];
    const float* xl = x + (size_t)(b * 128 + 64) * HW + j;
    float v[C2]; float ss = 0.f;
#pragma unroll
    for (int c = 0; c < C2; c++) { float w = xl[(size_t)c * HW]; v[c] = w; ss = fmaf(w, w, ss); }
    float inv = 1.0f / fmaxf(sqrtf(ss), EPSN);
    float* bp = bmat + (size_t)(b * HW + jj) * C2;
#pragma unroll
    for (int c = 0; c < C2; c++) bp[c] = v[c] * inv;
}

// ---------------- kernel 4: main argmax-"GEMM" ----------------------------
// lane owns one compacted i (a-vector in 64 VGPRs); b-vector address is
// wave-uniform -> scalar/broadcast loads; 64 fmaf + compare per j.
__global__ __launch_bounds__(256) void argmax_kernel(
    const float* __restrict__ x, const float* __restrict__ bmat,
    const int* __restrict__ ilist, const int* __restrict__ counts,
    float* __restrict__ pval, int* __restrict__ pidx)
{
    int b = blockIdx.z;
    int s = blockIdx.y;
    int ci = blockIdx.x * 256 + threadIdx.x;
    int ni = counts[0], nj = counts[1];
    if (blockIdx.x * 256 >= ni) return;          // fully-idle block
    bool valid = (ci < ni);
    int i = valid ? ilist[ci] : ilist[ni - 1];   // clamp for tail lanes
    const float* xb = x + (size_t)(b * 128 + 64) * HW + i;
    float a[C2];
#pragma unroll
    for (int c = 0; c < C2; c++) a[c] = xb[(size_t)c * HW];

    int chunk = (nj + NCHUNK - 1) / NCHUNK;
    int j0 = s * chunk;
    int j1 = min(j0 + chunk, nj);
    const float* bp = bmat + (size_t)(b * HW + j0) * C2;
    float best = -INFINITY; int bestjj = -1;
    for (int jj = j0; jj < j1; ++jj) {
        float s0 = 0.f, s1 = 0.f, s2 = 0.f, s3 = 0.f;
#pragma unroll
        for (int c = 0; c < C2; c += 4) {
            s0 = fmaf(a[c + 0], bp[c + 0], s0);
            s1 = fmaf(a[c + 1], bp[c + 1], s1);
            s2 = fmaf(a[c + 2], bp[c + 2], s2);
            s3 = fmaf(a[c + 3], bp[c + 3], s3);
        }
        float dot = (s0 + s1) + (s2 + s3);
        if (dot > best) { best = dot; bestjj = jj; }   // strict > keeps first max
        bp += C2;
    }
    if (valid) {
        int o = (b * NCHUNK + s) * HW + ci;
        pval[o] = best; pidx[o] = bestjj;
    }
}

// ---------------- kernel 5: reduce partials over chunks, map back ---------
__global__ void reduce_kernel(const float* __restrict__ pval, const int* __restrict__ pidx,
                              const int* __restrict__ ilist, const int* __restrict__ jlist,
                              const int* __restrict__ counts, int* __restrict__ idxbuf) {
    int t = blockIdx.x * blockDim.x + threadIdx.x;   // 0 .. 2*HW-1
    if (t >= 2 * HW) return;
    int b = t / HW, ci = t - b * HW;
    int ni = counts[0];
    if (ci >= ni) return;
    float best = -INFINITY; int bj = -1;
    for (int s = 0; s < NCHUNK; s++) {               // ascending chunks preserve first-max
        int o = (b * NCHUNK + s) * HW + ci;
        float v = pval[o];
        if (v > best) { best = v; bj = pidx[o]; }
    }
    int j = (bj >= 0) ? jlist[bj] : 0;               // nj==0 -> argmax of all-NEG row is 0
    idxbuf[b * HW + ilist[ci]] = j;
}

// ---------------- kernel 6: gather former -> shift channels ---------------
__global__ void gather_kernel(const float* __restrict__ x, const int* __restrict__ mask,
                              const int* __restrict__ idxbuf, float* __restrict__ out) {
    int t = blockIdx.x * blockDim.x + threadIdx.x;   // 0 .. 2*64*HW-1
    if (t >= 2 * C2 * HW) return;
    int pos = t % HW;
    int c = (t / HW) % C2;
    int b = t / (C2 * HW);
    float v = 0.f;
    if (mask[pos] >= 1) {
        int j = idxbuf[b * HW + pos];
        v = x[(size_t)(b * 128 + c) * HW + j];
    }
    out[(size_t)(b * 192 + 128 + c) * HW + pos] = v;
}

extern "C" void kernel_launch(void* const* d_in, const int* in_sizes, int n_in,
                              void* d_out, int out_size, void* d_ws, size_t ws_size,
                              hipStream_t stream) {
    const float* x = (const float*)d_in[0];
    const int* mask = (const int*)d_in[1];
    float* out = (float*)d_out;

    // workspace layout (all offsets 64B-aligned)
    char* ws = (char*)d_ws;
    int*   counts = (int*)ws;                                // 2 ints (pad to 64)
    int*   ilist  = (int*)(ws + 64);                         // HW ints = 36864 B
    int*   jlist  = (int*)(ws + 64 + 36864);                 // HW ints
    int*   idxbuf = (int*)(ws + 64 + 2 * 36864);             // 2*HW ints = 73728 B
    float* pval   = (float*)(ws + 64 + 2 * 36864 + 73728);                 // 2*16*HW f = 1179648 B
    int*   pidx   = (int*)  (ws + 64 + 2 * 36864 + 73728 + 1179648);       // 1179648 B
    float* bmat   = (float*)(ws + 64 + 2 * 36864 + 73728 + 2 * 1179648);   // 2*HW*64 f = 4718592 B

    // 1) passthrough copy (independent of the rest)
    {
        int n4 = 2 * 128 * HW / 4;
        copy_kernel<<<(n4 + 255) / 256, 256, 0, stream>>>((const float4*)x, (float4*)out);
    }
    // 2) compaction
    compact_kernel<<<1, 1024, 0, stream>>>(mask, ilist, jlist, counts);
    // 3) normalized compacted B
    buildb_kernel<<<(2 * HW + 255) / 256, 256, 0, stream>>>(x, jlist, counts, bmat);
    // 4) argmax GEMM: grid (i-blocks, j-chunks, batch)
    {
        dim3 grid((HW + 255) / 256, NCHUNK, 2);
        argmax_kernel<<<grid, 256, 0, stream>>>(x, bmat, ilist, counts, pval, pidx);
    }
    // 5) reduce chunks
    reduce_kernel<<<(2 * HW + 255) / 256, 256, 0, stream>>>(pval, pidx, ilist, jlist, counts, idxbuf);
    // 6) gather shift channels
    gather_kernel<<<(2 * C2 * HW + 255) / 256, 256, 0, stream>>>(x, mask, idxbuf, out);
}

// Round 2
// 208.790 us; speedup vs baseline: 1.2856x; 1.2856x over previous
//
#include <hip/hip_runtime.h>
#include <hip/hip_bf16.h>
#include <math.h>

#define HW 9216      // 96*96
#define C2 64
#define NCHUNK 32    // j-split factor
#define EPSN 1e-8f

// ---------------- kernel 1: compaction (single block, 1024 threads) -------
// ilist = positions with mask>=1 (flagged i), jlist = positions with mask<1
__global__ void compact_kernel(const int* __restrict__ mask, int* __restrict__ ilist,
                               int* __restrict__ jlist, int* __restrict__ counts) {
    __shared__ int sc[1024];
    int t = threadIdx.x;
    int base = t * 9;
    int f[9]; int cnt = 0;
#pragma unroll
    for (int k = 0; k < 9; k++) { f[k] = (mask[base + k] >= 1) ? 1 : 0; cnt += f[k]; }
    sc[t] = cnt;
    __syncthreads();
#pragma unroll
    for (int off = 1; off < 1024; off <<= 1) {
        int add = (t >= off) ? sc[t - off] : 0;
        __syncthreads();
        sc[t] += add;
        __syncthreads();
    }
    int incl = sc[t];
    int excl = incl - cnt;
    int posF = excl, posU = base - excl;
#pragma unroll
    for (int k = 0; k < 9; k++) {
        int p = base + k;
        if (f[k]) ilist[posF++] = p; else jlist[posU++] = p;
    }
    if (t == 1023) { counts[0] = incl; counts[1] = HW - incl; }
}

// ---------------- kernel 2: build normalized, compacted B matrix ----------
// bmat[b][jj][c] = lat[b][jlist[jj]][c] / max(||lat_j||, eps)  (contiguous 64f per jj)
__global__ void buildb_kernel(const float* __restrict__ x, const int* __restrict__ jlist,
                              const int* __restrict__ counts, float* __restrict__ bmat) {
    int t = blockIdx.x * blockDim.x + threadIdx.x;   // 0 .. 2*HW-1
    if (t >= 2 * HW) return;
    int b = t / HW, jj = t - b * HW;
    int nj = counts[1];
    if (jj >= nj) return;
    int j = jlist[jj];
    const float* xl = x + (size_t)(b * 128 + 64) * HW + j;
    float v[C2]; float ss = 0.f;
#pragma unroll
    for (int c = 0; c < C2; c++) { float w = xl[(size_t)c * HW]; v[c] = w; ss = fmaf(w, w, ss); }
    float inv = 1.0f / fmaxf(sqrtf(ss), EPSN);
    float* bp = bmat + (size_t)(b * HW + jj) * C2;
#pragma unroll
    for (int c = 0; c < C2; c++) bp[c] = v[c] * inv;
}

// ordered-float mapping: monotone bijection float -> uint32 under unsigned compare
__device__ __forceinline__ unsigned int ordf(float f) {
    unsigned int u = __float_as_uint(f);
    return (u & 0x80000000u) ? ~u : (u | 0x80000000u);
}

// ---------------- kernel 3: main argmax-"GEMM" ----------------------------
// lane owns one compacted i (a-vector in 64 VGPRs, forced by launch_bounds);
// b-vector address is wave-uniform -> scalar broadcast loads. Dual-j inner
// loop: 8 independent accumulators for ILP. Result merged via packed-u64
// atomicMax: key = ord(val)<<32 | ~jj  (ties -> smaller jj = first max).
__global__ __launch_bounds__(256, 4) void argmax_kernel(
    const float* __restrict__ x, const float* __restrict__ bmat,
    const int* __restrict__ ilist, const int* __restrict__ counts,
    unsigned long long* __restrict__ amax)
{
    int b = blockIdx.z;
    int s = blockIdx.y;
    int ci = blockIdx.x * 256 + threadIdx.x;
    int ni = counts[0], nj = counts[1];
    if (blockIdx.x * 256 >= ni) return;          // fully-idle block
    bool valid = (ci < ni);
    int i = ilist[valid ? ci : ni - 1];          // clamp for tail lanes
    const float* xb = x + (size_t)(b * 128 + 64) * HW + i;
    float a[C2];
#pragma unroll
    for (int c = 0; c < C2; c++) a[c] = xb[(size_t)c * HW];

    int chunk = (nj + NCHUNK - 1) / NCHUNK;
    int j0 = s * chunk;
    int j1 = min(j0 + chunk, nj);
    float best = -INFINITY; int bestjj = -1;
    const float* bp = bmat + ((size_t)b * HW + j0) * C2;
    int jj = j0;
    for (; jj + 2 <= j1; jj += 2, bp += 2 * C2) {
        float p0 = 0.f, p1 = 0.f, p2 = 0.f, p3 = 0.f;
        float q0 = 0.f, q1 = 0.f, q2 = 0.f, q3 = 0.f;
#pragma unroll
        for (int c = 0; c < C2; c += 4) {
            p0 = fmaf(a[c + 0], bp[c + 0], p0);
            p1 = fmaf(a[c + 1], bp[c + 1], p1);
            p2 = fmaf(a[c + 2], bp[c + 2], p2);
            p3 = fmaf(a[c + 3], bp[c + 3], p3);
            q0 = fmaf(a[c + 0], bp[C2 + c + 0], q0);
            q1 = fmaf(a[c + 1], bp[C2 + c + 1], q1);
            q2 = fmaf(a[c + 2], bp[C2 + c + 2], q2);
            q3 = fmaf(a[c + 3], bp[C2 + c + 3], q3);
        }
        float d0 = (p0 + p1) + (p2 + p3);
        float d1 = (q0 + q1) + (q2 + q3);
        if (d0 > best) { best = d0; bestjj = jj; }       // strict > keeps first max
        if (d1 > best) { best = d1; bestjj = jj + 1; }
    }
    if (jj < j1) {                                       // odd tail
        float p0 = 0.f, p1 = 0.f, p2 = 0.f, p3 = 0.f;
#pragma unroll
        for (int c = 0; c < C2; c += 4) {
            p0 = fmaf(a[c + 0], bp[c + 0], p0);
            p1 = fmaf(a[c + 1], bp[c + 1], p1);
            p2 = fmaf(a[c + 2], bp[c + 2], p2);
            p3 = fmaf(a[c + 3], bp[c + 3], p3);
        }
        float d0 = (p0 + p1) + (p2 + p3);
        if (d0 > best) { best = d0; bestjj = jj; }
    }
    if (valid && bestjj >= 0) {
        unsigned long long key = ((unsigned long long)ordf(best) << 32) |
                                 (unsigned long long)(~(unsigned int)bestjj);
        atomicMax(&amax[(size_t)b * HW + i], key);       // indexed by ORIGINAL position
    }
}

// ---------------- kernel 4: fused epilogue (copy + decode + gather) -------
// out channels [0,128): passthrough copy of x.
// out channels [128,192): shift = gathered former at argmax j (0 where !flag).
__global__ void epilogue_kernel(const float* __restrict__ x, const int* __restrict__ mask,
                                const unsigned long long* __restrict__ amax,
                                const int* __restrict__ jlist, float* __restrict__ out) {
    int t = blockIdx.x * blockDim.x + threadIdx.x;   // 0 .. 2*192*HW-1
    if (t >= 2 * 192 * HW) return;
    int pos = t % HW;
    int c = (t / HW) % 192;
    int b = t / (192 * HW);
    float v;
    if (c < 128) {
        v = x[(size_t)(b * 128 + c) * HW + pos];
    } else {
        v = 0.f;
        if (mask[pos] >= 1) {
            unsigned long long key = amax[(size_t)b * HW + pos];
            int j = 0;                               // nj==0 -> argmax of all-NEG row = 0
            if (key != 0ull) {
                int jj = (int)(~(unsigned int)key);
                j = jlist[jj];
            }
            v = x[(size_t)(b * 128 + (c - 128)) * HW + j];
        }
    }
    out[t] = v;
}

extern "C" void kernel_launch(void* const* d_in, const int* in_sizes, int n_in,
                              void* d_out, int out_size, void* d_ws, size_t ws_size,
                              hipStream_t stream) {
    const float* x = (const float*)d_in[0];
    const int* mask = (const int*)d_in[1];
    float* out = (float*)d_out;

    // workspace layout (64B-aligned): counts | ilist | jlist | amax | bmat
    char* ws = (char*)d_ws;
    int*   counts = (int*)ws;                                  // 2 ints (pad to 64)
    int*   ilist  = (int*)(ws + 64);                           // HW ints = 36864 B
    int*   jlist  = (int*)(ws + 64 + 36864);                   // HW ints
    unsigned long long* amax = (unsigned long long*)(ws + 64 + 2 * 36864);      // 2*HW*8 = 147456 B
    float* bmat   = (float*)(ws + 64 + 2 * 36864 + 147456);    // 2*HW*64*4 = 4718592 B

    // zero the argmax merge buffer (ws is poisoned 0xAA before every launch)
    hipMemsetAsync(amax, 0, (size_t)2 * HW * 8, stream);
    // 1) compaction
    compact_kernel<<<1, 1024, 0, stream>>>(mask, ilist, jlist, counts);
    // 2) normalized compacted B
    buildb_kernel<<<(2 * HW + 255) / 256, 256, 0, stream>>>(x, jlist, counts, bmat);
    // 3) argmax GEMM: grid (i-blocks, j-chunks, batch)
    {
        dim3 grid((HW + 255) / 256, NCHUNK, 2);
        argmax_kernel<<<grid, 256, 0, stream>>>(x, bmat, ilist, counts, amax);
    }
    // 4) fused copy + decode + gather
    {
        int n = 2 * 192 * HW;
        epilogue_kernel<<<(n + 255) / 256, 256, 0, stream>>>(x, mask, amax, jlist, out);
    }
}

// Round 3
// 188.231 us; speedup vs baseline: 1.4261x; 1.1092x over previous
//
#include <hip/hip_runtime.h>
#include <hip/hip_bf16.h>
#include <math.h>

#define HW 9216      // 96*96
#define C2 64
#define NCHUNK 64    // j-split factor
#define JTILE 32     // j-tile per lane (32 accumulators)
#define EPSN 1e-8f

// ---------------- kernel 1: compaction + amax zero (single block) ---------
// ilist = positions with mask>=1 (flagged i), jlist = positions with mask<1
__global__ void compact_kernel(const int* __restrict__ mask, int* __restrict__ ilist,
                               int* __restrict__ jlist, int* __restrict__ counts,
                               unsigned long long* __restrict__ amax) {
    __shared__ int sc[1024];
    int t = threadIdx.x;
    // zero the argmax merge buffer (ws is poisoned 0xAA before every launch)
#pragma unroll
    for (int k = 0; k < 18; k++) amax[t * 18 + k] = 0ull;   // 1024*18 = 2*HW
    int base = t * 9;
    int f[9]; int cnt = 0;
#pragma unroll
    for (int k = 0; k < 9; k++) { f[k] = (mask[base + k] >= 1) ? 1 : 0; cnt += f[k]; }
    sc[t] = cnt;
    __syncthreads();
#pragma unroll
    for (int off = 1; off < 1024; off <<= 1) {
        int add = (t >= off) ? sc[t - off] : 0;
        __syncthreads();
        sc[t] += add;
        __syncthreads();
    }
    int incl = sc[t];
    int excl = incl - cnt;
    int posF = excl, posU = base - excl;
#pragma unroll
    for (int k = 0; k < 9; k++) {
        int p = base + k;
        if (f[k]) ilist[posF++] = p; else jlist[posU++] = p;
    }
    if (t == 1023) { counts[0] = incl; counts[1] = HW - incl; }
}

// ---------------- kernel 2: build transposed compacted A and B ------------
// amatT[b][c][ci] = lat[b][c][ilist[ci]]                    (unnormalized)
// bmatT[b][c][jj] = lat[b][c][jlist[jj]] / max(||lat_j||,eps)
// zero-padded to HW columns so argmax tails read benign zeros.
__global__ void buildab_kernel(const float* __restrict__ x, const int* __restrict__ ilist,
                               const int* __restrict__ jlist, const int* __restrict__ counts,
                               float* __restrict__ amatT, float* __restrict__ bmatT) {
    int t = blockIdx.x * blockDim.x + threadIdx.x;   // 0 .. 4*HW-1
    if (t >= 4 * HW) return;
    int kind = t / (2 * HW);                         // 0 = A, 1 = B
    int r = t - kind * 2 * HW;
    int b = r / HW, p = r - b * HW;
    int n = kind ? counts[1] : counts[0];
    float v[C2];
    if (p < n) {
        int src = kind ? jlist[p] : ilist[p];
        const float* xl = x + (size_t)(b * 128 + 64) * HW + src;
        float ss = 0.f;
#pragma unroll
        for (int c = 0; c < C2; c++) { float w = xl[(size_t)c * HW]; v[c] = w; ss = fmaf(w, w, ss); }
        if (kind) {
            float inv = 1.0f / fmaxf(sqrtf(ss), EPSN);
#pragma unroll
            for (int c = 0; c < C2; c++) v[c] *= inv;
        }
    } else {
#pragma unroll
        for (int c = 0; c < C2; c++) v[c] = 0.f;
    }
    float* d = (kind ? bmatT : amatT) + (size_t)b * C2 * HW + p;
#pragma unroll
    for (int c = 0; c < C2; c++) d[(size_t)c * HW] = v[c];
}

// ordered-float mapping: monotone bijection float -> uint32 under unsigned compare
__device__ __forceinline__ unsigned int ordf(float f) {
    unsigned int u = __float_as_uint(f);
    return (u & 0x80000000u) ? ~u : (u | 0x80000000u);
}

// ---------------- kernel 3: main argmax-"GEMM" (register-tiled) -----------
// Lane owns one ci and a 32-wide j-tile of loop-carried accumulators (can't
// be remat'd). Per c: 1 coalesced a-load + 32 FMAs; b-values are wave-uniform
// -> scalar loads on the SMEM pipe. First-max tie-break: ascending jb/k,
// strict >, merged via packed-u64 atomicMax (key = ord(val)<<32 | ~jj).
__global__ __launch_bounds__(256, 4) void argmax_kernel(
    const float* __restrict__ amatT, const float* __restrict__ bmatT,
    const int* __restrict__ ilist, const int* __restrict__ counts,
    unsigned long long* __restrict__ amax)
{
    int b = blockIdx.z;
    int s = blockIdx.y;
    int ci = blockIdx.x * 256 + threadIdx.x;
    int ni = counts[0], nj = counts[1];
    if (blockIdx.x * 256 >= ni) return;              // dead block
    int chunk = (((nj + NCHUNK - 1) / NCHUNK) + 15) & ~15;   // mult of 16 for s_load alignment
    int j0 = s * chunk;
    int j1 = min(j0 + chunk, nj);
    const float* ap = amatT + (size_t)b * C2 * HW + ci;
    const float* bbase = bmatT + (size_t)b * C2 * HW;
    float best = -INFINITY; int bestjj = -1;
    for (int jb = j0; jb < j1; jb += JTILE) {
        float acc[JTILE];
#pragma unroll
        for (int k = 0; k < JTILE; k++) acc[k] = 0.f;
        const float* bp = bbase + jb;
#pragma unroll 4
        for (int c = 0; c < C2; c++) {
            float av = ap[(size_t)c * HW];
            const float* bc = bp + (size_t)c * HW;
#pragma unroll
            for (int k = 0; k < JTILE; k++) acc[k] = fmaf(av, bc[k], acc[k]);
        }
        int lim = j1 - jb;                            // tail guard (padded cols are zeros)
#pragma unroll
        for (int k = 0; k < JTILE; k++)
            if (k < lim && acc[k] > best) { best = acc[k]; bestjj = jb + k; }
    }
    if (ci < ni && bestjj >= 0) {
        unsigned long long key = ((unsigned long long)ordf(best) << 32) |
                                 (unsigned long long)(~(unsigned int)bestjj);
        atomicMax(&amax[(size_t)b * HW + ilist[ci]], key);   // indexed by ORIGINAL position
    }
}

// ---------------- kernel 4: fused epilogue (copy + decode + gather) -------
// out channels [0,128): passthrough copy of x (float4).
// out channels [128,192): shift = former at argmax j (0 where !flag).
__global__ void epilogue_kernel(const float4* __restrict__ x4, const float* __restrict__ x,
                                const int* __restrict__ mask,
                                const unsigned long long* __restrict__ amax,
                                const int* __restrict__ jlist, float4* __restrict__ out4) {
    const int q = HW / 4;                            // 2304
    int t = blockIdx.x * blockDim.x + threadIdx.x;   // 0 .. 2*192*q-1
    if (t >= 2 * 192 * q) return;
    int pos4 = t % q;
    int c = (t / q) % 192;
    int b = t / (192 * q);
    if (c < 128) {
        out4[t] = x4[((size_t)b * 128 + c) * q + pos4];
    } else {
        float4 v = make_float4(0.f, 0.f, 0.f, 0.f);
        float* vp = &v.x;
        int pos = pos4 * 4;
        const float* xf = x + (size_t)(b * 128 + (c - 128)) * HW;
#pragma unroll
        for (int k = 0; k < 4; k++) {
            int p = pos + k;
            if (mask[p] >= 1) {
                unsigned long long key = amax[(size_t)b * HW + p];
                int j = 0;                           // nj==0 -> argmax of all-NEG row = 0
                if (key != 0ull) j = jlist[(int)(~(unsigned int)key)];
                vp[k] = xf[j];
            }
        }
        out4[t] = v;
    }
}

extern "C" void kernel_launch(void* const* d_in, const int* in_sizes, int n_in,
                              void* d_out, int out_size, void* d_ws, size_t ws_size,
                              hipStream_t stream) {
    const float* x = (const float*)d_in[0];
    const int* mask = (const int*)d_in[1];
    float4* out4 = (float4*)d_out;

    // workspace layout (64B-aligned): counts | ilist | jlist | amax | amatT | bmatT
    char* ws = (char*)d_ws;
    int*   counts = (int*)ws;                                   // 2 ints (pad to 64)
    int*   ilist  = (int*)(ws + 64);                            // HW ints = 36864 B
    int*   jlist  = (int*)(ws + 64 + 36864);                    // HW ints
    unsigned long long* amax = (unsigned long long*)(ws + 64 + 2 * 36864);   // 2*HW*8 = 147456 B
    float* amatT  = (float*)(ws + 64 + 2 * 36864 + 147456);                  // 2*64*HW*4 = 4718592 B
    float* bmatT  = (float*)(ws + 64 + 2 * 36864 + 147456 + 4718592);        // 4718592 B

    // 1) compaction + amax zeroing
    compact_kernel<<<1, 1024, 0, stream>>>(mask, ilist, jlist, counts, amax);
    // 2) transposed compacted A and normalized B
    buildab_kernel<<<(4 * HW + 255) / 256, 256, 0, stream>>>(x, ilist, jlist, counts, amatT, bmatT);
    // 3) argmax GEMM: grid (i-blocks, j-chunks, batch)
    {
        dim3 grid((HW + 255) / 256, NCHUNK, 2);
        argmax_kernel<<<grid, 256, 0, stream>>>(amatT, bmatT, ilist, counts, amax);
    }
    // 4) fused copy + decode + gather
    {
        int n = 2 * 192 * (HW / 4);
        epilogue_kernel<<<(n + 255) / 256, 256, 0, stream>>>((const float4*)x, x, mask, amax, jlist, out4);
    }
}